// Round 1
// baseline (1346.481 us; speedup 1.0000x reference)
//
#include <hip/hip_runtime.h>
#include <stdint.h>

// Problem constants: B=128, D0=2048, D1=512, R=4, F=64, RF=256
// out[b,f] = sum_{i,j,r} jac[b,i,j] * Ub[j,r,f] * Ua[i,r,f]  (both jacs summed)
// GEMM1: [B*D0, D1] x [D1, 256]   (jac1, U1b), epilogue with U1a
// GEMM2: [B*D1, D0] x [D0, 256]   (jac2, U2b), epilogue with U2a

#define BM 128
#define BN 256
#define BK 64
#define LDK 72   // BK + 8 pad (bf16 units) to break bank conflicts on ds_read_b128

typedef __attribute__((ext_vector_type(8))) __bf16 bf16x8;
typedef __attribute__((ext_vector_type(4))) float floatx4;

__device__ __forceinline__ unsigned short f32_to_bf16_rne(float x) {
    union { float f; unsigned int u; } v; v.f = x;
    unsigned int r = v.u + 0x7fffu + ((v.u >> 16) & 1u);
    return (unsigned short)(r >> 16);
}

__global__ void zero_out(float* __restrict__ out) {
    int idx = blockIdx.x * blockDim.x + threadIdx.x;
    if (idx < 128 * 64) out[idx] = 0.0f;
}

// U: [K][256] fp32  ->  W: [256][K] bf16-bits  (B^T layout so B-frag stages as 16B copies)
__global__ void transpose_cast(const float* __restrict__ U,
                               unsigned short* __restrict__ W,
                               int K, int kshift) {
    int idx = blockIdx.x * blockDim.x + threadIdx.x;   // over 256*K, writes coalesced
    int n = idx >> kshift;
    int k = idx & (K - 1);
    W[idx] = f32_to_bf16_rne(U[(size_t)k * 256 + n]);
}

__global__ __launch_bounds__(256, 2)
void gemm_fused(const float* __restrict__ jac,        // [Mrows][K] fp32
                const unsigned short* __restrict__ W, // [256][K] bf16 bits (B^T)
                const float* __restrict__ Ua,         // [M_per_b dim][256] fp32
                float* __restrict__ out,              // [128][64] fp32
                int K, int mshift /* log2(rows per batch) */) {
    __shared__ unsigned short As[BM * LDK];
    __shared__ unsigned short Bs[BN * LDK];

    const int tid  = threadIdx.x;
    const int wave = tid >> 6;     // 0..3  -> rf range [64w, 64w+64), i.e. r = wave
    const int lane = tid & 63;
    const int quad = lane >> 4;    // 0..3
    const int ln   = lane & 15;

    const int row0 = blockIdx.x * BM;           // global jac row base
    const int b    = row0 >> mshift;            // batch index (BM divides rows/batch)
    const int i0   = row0 & ((1 << mshift) - 1);// i base within this batch

    floatx4 acc[8][4];
    #pragma unroll
    for (int mt = 0; mt < 8; ++mt)
        #pragma unroll
        for (int nt = 0; nt < 4; ++nt)
            acc[mt][nt] = (floatx4){0.f, 0.f, 0.f, 0.f};

    const int nstages = K >> 6;   // K / BK
    for (int kt = 0; kt < nstages; ++kt) {
        const int k0 = kt * BK;

        // --- stage A: 128 x 64 fp32 -> bf16 LDS (row-major, k contiguous) ---
        #pragma unroll
        for (int p = 0; p < 8; ++p) {
            int idx = tid + p * 256;     // 0..2047
            int r = idx >> 4;            // 0..127
            int c = idx & 15;            // float4 column, k = 4c
            const floatx4 v = *(const floatx4*)(jac + (size_t)(row0 + r) * K + k0 + c * 4);
            unsigned int lo = (unsigned int)f32_to_bf16_rne(v[0]) |
                              ((unsigned int)f32_to_bf16_rne(v[1]) << 16);
            unsigned int hi = (unsigned int)f32_to_bf16_rne(v[2]) |
                              ((unsigned int)f32_to_bf16_rne(v[3]) << 16);
            uint2 w; w.x = lo; w.y = hi;
            *(uint2*)&As[r * LDK + c * 4] = w;   // ds_write_b64
        }
        // --- stage B: 256 x 64 bf16, already transposed, pure 16B copies ---
        #pragma unroll
        for (int p = 0; p < 8; ++p) {
            int idx = tid + p * 256;     // 0..2047
            int r = idx >> 3;            // 0..255 (rf row)
            int c = idx & 7;             // 8-elem column, k = 8c
            const uint4 v = *(const uint4*)(W + (size_t)r * K + k0 + c * 8);
            *(uint4*)&Bs[r * LDK + c * 8] = v;   // ds_write_b128
        }
        __syncthreads();

        #pragma unroll
        for (int ks = 0; ks < 2; ++ks) {
            bf16x8 a[8], bb[4];
            #pragma unroll
            for (int mt = 0; mt < 8; ++mt)
                a[mt] = *(const bf16x8*)&As[(mt * 16 + ln) * LDK + ks * 32 + quad * 8];
            #pragma unroll
            for (int nt = 0; nt < 4; ++nt)
                bb[nt] = *(const bf16x8*)&Bs[(wave * 64 + nt * 16 + ln) * LDK + ks * 32 + quad * 8];
            #pragma unroll
            for (int mt = 0; mt < 8; ++mt)
                #pragma unroll
                for (int nt = 0; nt < 4; ++nt)
                    acc[mt][nt] = __builtin_amdgcn_mfma_f32_16x16x32_bf16(
                        a[mt], bb[nt], acc[mt][nt], 0, 0, 0);
        }
        __syncthreads();
    }

    // --- epilogue: out[b,f] += sum_{i in tile, rf} acc * Ua[i, rf] ---
    // C/D layout: col = lane&15 (n side), row = quad*4 + reg (m side)
    float psum[4] = {0.f, 0.f, 0.f, 0.f};
    #pragma unroll
    for (int mt = 0; mt < 8; ++mt) {
        const int irow = i0 + mt * 16 + quad * 4;
        #pragma unroll
        for (int nt = 0; nt < 4; ++nt) {
            const int col = wave * 64 + nt * 16 + ln;   // rf index
            #pragma unroll
            for (int reg = 0; reg < 4; ++reg)
                psum[nt] += acc[mt][nt][reg] * Ua[(size_t)(irow + reg) * 256 + col];
        }
    }
    #pragma unroll
    for (int nt = 0; nt < 4; ++nt) {
        float v = psum[nt];
        v += __shfl_xor(v, 16);   // reduce across quads (rows), col preserved
        v += __shfl_xor(v, 32);
        if (lane < 16) atomicAdd(&out[b * 64 + nt * 16 + ln], v);  // f = nt*16+ln
    }
}

extern "C" void kernel_launch(void* const* d_in, const int* in_sizes, int n_in,
                              void* d_out, int out_size, void* d_ws, size_t ws_size,
                              hipStream_t stream) {
    const float* jac1 = (const float*)d_in[0];   // [128, 2048, 512]
    const float* jac2 = (const float*)d_in[1];   // [128, 512, 2048]
    const float* U1a  = (const float*)d_in[2];   // [2048, 256]
    const float* U1b  = (const float*)d_in[3];   // [512, 256]
    const float* U2a  = (const float*)d_in[4];   // [512, 256]
    const float* U2b  = (const float*)d_in[5];   // [2048, 256]
    float* out = (float*)d_out;                  // [128, 64]

    unsigned short* W1 = (unsigned short*)d_ws;  // [256][512]  bf16, 256 KB
    unsigned short* W2 = W1 + 256 * 512;         // [256][2048] bf16, 1 MB

    zero_out<<<32, 256, 0, stream>>>(out);
    transpose_cast<<<512,  256, 0, stream>>>(U1b, W1, 512, 9);
    transpose_cast<<<2048, 256, 0, stream>>>(U2b, W2, 2048, 11);

    // jac1: M = 128*2048 = 262144 rows, K = 512, 2048 blocks
    gemm_fused<<<2048, 256, 0, stream>>>(jac1, W1, U1a, out, 512, 11);
    // jac2: M = 128*512 = 65536 rows, K = 2048, 512 blocks
    gemm_fused<<<512, 256, 0, stream>>>(jac2, W2, U2a, out, 2048, 9);
}

// Round 2
// 1076.004 us; speedup vs baseline: 1.2514x; 1.2514x over previous
//
#include <hip/hip_runtime.h>
#include <stdint.h>

// Problem: B=128, D0=2048, D1=512, R=4, F=64, RF=256
// out[b,f] = sum_{i,j,r} jac[b,i,j] * Ub[j,rf] * Ua[i,rf]  (both params summed)
// GEMM1: [B*D0, 512] x [512, 256]  ; GEMM2: [B*D1, 2048] x [2048, 256]
// HBM-bound: 1.07 GB jac stream -> 170 us floor. Everything serves BW saturation.

#define BM 128
#define BN 256
#define BK 64

typedef __attribute__((ext_vector_type(8))) __bf16 bf16x8;
typedef __attribute__((ext_vector_type(4))) float floatx4;

__device__ __forceinline__ unsigned short f32_to_bf16_rne(float x) {
    union { float f; unsigned int u; } v; v.f = x;
    unsigned int r = v.u + 0x7fffu + ((v.u >> 16) & 1u);
    return (unsigned short)(r >> 16);
}

// round-half-up bf16 pack of two floats: low half = x, high half = y. 3 VALU.
__device__ __forceinline__ unsigned int pack2_bf16(float x, float y) {
    union { float f; unsigned int u; } a, b; a.f = x; b.f = y;
    return __builtin_amdgcn_perm(b.u + 0x8000u, a.u + 0x8000u, 0x07060302u);
}

__device__ __forceinline__ void async_copy16(const void* g, void* l) {
    __builtin_amdgcn_global_load_lds(
        (const __attribute__((address_space(1))) unsigned int*)g,
        (__attribute__((address_space(3))) unsigned int*)l, 16, 0, 0);
}

__global__ void zero_out(float* __restrict__ out) {
    int idx = blockIdx.x * blockDim.x + threadIdx.x;
    if (idx < 128 * 64) out[idx] = 0.0f;
}

// U: [K][256] fp32 -> W: [256][K] bf16 bits (B^T: k contiguous per rf row)
__global__ void transpose_cast(const float* __restrict__ U,
                               unsigned short* __restrict__ W,
                               int K, int kshift) {
    int idx = blockIdx.x * blockDim.x + threadIdx.x;
    int n = idx >> kshift;
    int k = idx & (K - 1);
    W[idx] = f32_to_bf16_rne(U[(size_t)k * 256 + n]);
}

// LDS layout (both As, Bs): row r of 64 bf16 = 8 chunks of 16B.
// logical chunk cl stored at physical cp = cl ^ (r&7)  (XOR swizzle:
// allows linear global_load_lds DMA AND minimum-phase ds_read_b128).
__global__ __launch_bounds__(256, 2)
void gemm_fused(const float* __restrict__ jac,        // [Mrows][K] fp32
                const unsigned short* __restrict__ W, // [256][K] bf16 bits (B^T)
                const float* __restrict__ Ua,         // [dim][256] fp32
                float* __restrict__ out,              // [128][64] fp32
                int K, int mshift /* log2(rows per batch) */) {
    __shared__ unsigned short As[BM * BK];   // 16 KB
    __shared__ unsigned short Bs[BN * BK];   // 32 KB

    const int tid  = threadIdx.x;
    const int wave = tid >> 6;     // 0..3 -> rf range [64w, 64w+64)
    const int lane = tid & 63;
    const int quad = lane >> 4;
    const int ln   = lane & 15;

    const int row0 = blockIdx.x * BM;
    const int b    = row0 >> mshift;
    const int i0   = row0 & ((1 << mshift) - 1);

    floatx4 acc[8][4];
    #pragma unroll
    for (int mt = 0; mt < 8; ++mt)
        #pragma unroll
        for (int nt = 0; nt < 4; ++nt)
            acc[mt][nt] = (floatx4){0.f, 0.f, 0.f, 0.f};

    const int nstages = K >> 6;
    const int ar = (tid >> 4);        // A row group base (16 rows per p-step)
    const int ac4 = tid & 15;         // A float4 column (k = 4*ac4)
    const float* aptr = jac + (size_t)(row0 + ar) * K + ac4 * 4;

    // prologue: A stage 0 into registers
    floatx4 av[8];
    #pragma unroll
    for (int p = 0; p < 8; ++p)
        av[p] = *(const floatx4*)(aptr + (size_t)(p * 16) * K);

    for (int kt = 0; kt < nstages; ++kt) {
        const int k0 = kt * BK;

        // --- B: async DMA global->LDS, 16B/lane, source-swizzled ---
        #pragma unroll
        for (int p = 0; p < 8; ++p) {
            int idx = p * 256 + tid;          // wave-contiguous: base + lane
            int r = idx >> 3;                 // rf row 0..255
            int cp = idx & 7;                 // physical chunk
            const unsigned short* src = W + (size_t)r * K + k0 + ((cp ^ (r & 7)) << 3);
            async_copy16(src, &Bs[idx * 8]);
        }

        // --- A: convert prefetched regs -> swizzled LDS (b64 writes) ---
        #pragma unroll
        for (int p = 0; p < 8; ++p) {
            int r = ar + p * 16;
            int up = ac4 ^ ((r & 7) << 1);    // physical 8B unit
            uint2 w;
            w.x = pack2_bf16(av[p][0], av[p][1]);
            w.y = pack2_bf16(av[p][2], av[p][3]);
            *(uint2*)&As[r * 64 + up * 4] = w;
        }
        __syncthreads();   // drains B DMA (vmcnt) + As writes (lgkmcnt)

        // --- A prefetch for next stage: streams during MFMA below ---
        {
            const int kn = (kt + 1 < nstages ? kt + 1 : kt) * BK;  // last iter: L2-hot re-read
            #pragma unroll
            for (int p = 0; p < 8; ++p)
                av[p] = *(const floatx4*)(aptr + (size_t)(p * 16) * K + kn);
        }

        // --- MFMA ---
        #pragma unroll
        for (int ks = 0; ks < 2; ++ks) {
            bf16x8 a[8], bb[4];
            #pragma unroll
            for (int mt = 0; mt < 8; ++mt) {
                int r = mt * 16 + ln;
                a[mt] = *(const bf16x8*)&As[r * 64 + (((ks * 4 + quad) ^ (r & 7)) << 3)];
            }
            #pragma unroll
            for (int nt = 0; nt < 4; ++nt) {
                int r = wave * 64 + nt * 16 + ln;
                bb[nt] = *(const bf16x8*)&Bs[r * 64 + (((ks * 4 + quad) ^ (r & 7)) << 3)];
            }
            #pragma unroll
            for (int mt = 0; mt < 8; ++mt)
                #pragma unroll
                for (int nt = 0; nt < 4; ++nt)
                    acc[mt][nt] = __builtin_amdgcn_mfma_f32_16x16x32_bf16(
                        a[mt], bb[nt], acc[mt][nt], 0, 0, 0);
        }
        __syncthreads();
    }

    // --- epilogue: out[b,f] += sum_{i,rf} acc * Ua[i, rf] ---
    // C/D layout: col = lane&15 (n/rf side), row = quad*4 + reg (m/i side)
    float psum[4] = {0.f, 0.f, 0.f, 0.f};
    #pragma unroll
    for (int mt = 0; mt < 8; ++mt) {
        const int irow = i0 + mt * 16 + quad * 4;
        #pragma unroll
        for (int nt = 0; nt < 4; ++nt) {
            const int col = wave * 64 + nt * 16 + ln;   // rf
            #pragma unroll
            for (int reg = 0; reg < 4; ++reg)
                psum[nt] += acc[mt][nt][reg] * Ua[(size_t)(irow + reg) * 256 + col];
        }
    }
    #pragma unroll
    for (int nt = 0; nt < 4; ++nt) {
        float v = psum[nt];
        v += __shfl_xor(v, 16);
        v += __shfl_xor(v, 32);
        if (lane < 16) atomicAdd(&out[b * 64 + nt * 16 + ln], v);  // f = nt*16+ln
    }
}

extern "C" void kernel_launch(void* const* d_in, const int* in_sizes, int n_in,
                              void* d_out, int out_size, void* d_ws, size_t ws_size,
                              hipStream_t stream) {
    const float* jac1 = (const float*)d_in[0];   // [128, 2048, 512]
    const float* jac2 = (const float*)d_in[1];   // [128, 512, 2048]
    const float* U1a  = (const float*)d_in[2];   // [2048, 256]
    const float* U1b  = (const float*)d_in[3];   // [512, 256]
    const float* U2a  = (const float*)d_in[4];   // [512, 256]
    const float* U2b  = (const float*)d_in[5];   // [2048, 256]
    float* out = (float*)d_out;                  // [128, 64]

    unsigned short* W1 = (unsigned short*)d_ws;  // [256][512]  bf16
    unsigned short* W2 = W1 + 256 * 512;         // [256][2048] bf16

    zero_out<<<32, 256, 0, stream>>>(out);
    transpose_cast<<<512,  256, 0, stream>>>(U1b, W1, 512, 9);
    transpose_cast<<<2048, 256, 0, stream>>>(U2b, W2, 2048, 11);

    // jac1: M = 262144 rows, K = 512
    gemm_fused<<<2048, 256, 0, stream>>>(jac1, W1, U1a, out, 512, 11);
    // jac2: M = 65536 rows, K = 2048
    gemm_fused<<<512, 256, 0, stream>>>(jac2, W2, U2a, out, 2048, 9);
}